// Round 7
// baseline (282.086 us; speedup 1.0000x reference)
//
#include <hip/hip_runtime.h>
#include <math.h>

typedef _Float16 f16;
typedef _Float16 f16x8 __attribute__((ext_vector_type(8)));
typedef float    f32x16 __attribute__((ext_vector_type(16)));
typedef unsigned int uint;
typedef unsigned short u16;

#define B_Q     1024
#define DIM     128
#define N_KEYS  100000
#define NPAD    102400          /* padded to 3200 groups of 32 */
#define NGP     (NPAD / 32)     /* 3200 */
#define KC      320             /* key chunks */
#define GPB     (NGP / KC)      /* 10 groups per block */
#define N_CLS   1000
#define QSCALE  11.541560327111707f /* 8/ln2: fold beta*log2(e) into queries */
#define CSUM    10
#define NCB     (N_CLS / CSUM)  /* 100 */

// ---- label histogram ----
__global__ void k_hist(const int* __restrict__ labels, uint* __restrict__ ghist) {
    __shared__ uint lh[N_CLS];
    for (int i = threadIdx.x; i < N_CLS; i += blockDim.x) lh[i] = 0;
    __syncthreads();
    const int stride = gridDim.x * blockDim.x;
    for (int i = blockIdx.x * blockDim.x + threadIdx.x; i < N_KEYS; i += stride)
        atomicAdd(&lh[labels[i]], 1u);
    __syncthreads();
    for (int i = threadIdx.x; i < N_CLS; i += blockDim.x)
        if (lh[i]) atomicAdd(&ghist[i], lh[i]);
}

// ---- exclusive scan -> cursor ----
__global__ void k_scan(const uint* __restrict__ ghist, uint* __restrict__ cursor) {
    __shared__ uint s[1024];
    const int t = threadIdx.x;
    const uint v = (t < N_CLS) ? ghist[t] : 0u;
    s[t] = v; __syncthreads();
    for (int o = 1; o < 1024; o <<= 1) {
        const uint x = (t >= o) ? s[t - o] : 0u;
        __syncthreads();
        s[t] += x;
        __syncthreads();
    }
    if (t < N_CLS) cursor[t] = s[t] - v;
}

// ---- fused prep: normalize, f16, scatter into MFMA-fragment order; dummies ----
// layout per 32-row group: [kk(8)][lane(64)][j(8)] f16; (kk,lane,j) =
// row (lane&31), dim kk*16 + (lane>>5)*8 + j.
__global__ void k_prep(const float* __restrict__ qm, const float* __restrict__ km,
                       const int* __restrict__ labels, uint* __restrict__ cursor,
                       f16* __restrict__ kf2, f16* __restrict__ qf2,
                       u16* __restrict__ kcls) {
    const int gid  = blockIdx.x * blockDim.x + threadIdx.x;
    const int n    = gid >> 6;
    const int lane = threadIdx.x & 63;
    if (n >= NPAD + B_Q) return;
    const bool isq   = n >= NPAD;
    const bool dummy = !isq && n >= N_KEYS;

    float a = 0.0f, b = 0.0f;
    if (!dummy) {
        const float* row = isq ? qm + (size_t)(n - NPAD) * DIM
                               : km + (size_t)n * DIM;
        a = row[lane]; b = row[lane + 64];
    }
    float ss = a * a + b * b;
    #pragma unroll
    for (int o = 32; o >= 1; o >>= 1) ss += __shfl_xor(ss, o);
    const float rn = (isq ? QSCALE : 1.0f) / fmaxf(sqrtf(ss), 1e-12f);

    int pos;
    if (isq)        pos = n - NPAD;
    else if (dummy) { pos = n; if (lane == 0) kcls[pos] = (u16)N_CLS; }
    else {
        const int lab = labels[n];
        if (lane == 0) pos = (int)atomicAdd(&cursor[lab], 1u);
        pos = __shfl(pos, 0);
        if (lane == 0) kcls[pos] = (u16)lab;
    }

    const float va = a * rn, vb = b * rn;   // dummy: 0 * 1e12 = 0
    f16x8 hv;
    #pragma unroll
    for (int j = 0; j < 8; ++j) {
        const int src = (lane & 15) * 8 + j;        // 0..127
        const float xa = __shfl(va, src & 63);
        const float xb = __shfl(vb, src & 63);
        hv[j] = (f16)((src < 64) ? xa : xb);
    }
    if (lane < 16) {
        f16* dst = isq ? qf2 : kf2;
        const int kk  = lane >> 1;
        const int lhi = lane & 1;
        *(f16x8*)(dst + (size_t)(pos >> 5) * 4096 + kk * 512 +
                  ((lhi << 5) + (pos & 31)) * 8) = hv;
    }
}

// ---- main: 1280 blocks (XCD co-located), 4 waves, 2 q-subtiles/wave,
// LDS-precomputed class metadata, double-buffered fragment-order tiles.
#define FLUSH(C) {                                                            \
    _Pragma("unroll")                                                         \
    for (int r = 0; r < 16; ++r) {                                            \
        float t0 = sums0[r], t1 = sums1[r];                                   \
        t0 += __shfl_xor(t0,1); t0 += __shfl_xor(t0,2); t0 += __shfl_xor(t0,4);\
        t0 += __shfl_xor(t0,8); t0 += __shfl_xor(t0,16);                      \
        t1 += __shfl_xor(t1,1); t1 += __shfl_xor(t1,2); t1 += __shfl_xor(t1,4);\
        t1 += __shfl_xor(t1,8); t1 += __shfl_xor(t1,16);                      \
        const int row = (r & 3) + 8 * (r >> 2) + 4 * lhi;                     \
        if (l31 == row) {                                                     \
            atomicAdd(&out_t[(size_t)(C) * B_Q + q00 + row], t0);             \
            atomicAdd(&out_t[(size_t)(C) * B_Q + q01 + row], t1);             \
        }                                                                     \
    } }
#define ZEROSUMS { _Pragma("unroll") for (int r=0;r<16;++r){sums0[r]=0.f;sums1[r]=0.f;} }

__global__ __launch_bounds__(256, 4)
void class_gemm4(const f16* __restrict__ kf2, const f16* __restrict__ qf2,
                 const u16* __restrict__ kcls, float* __restrict__ out_t) {
    __shared__ __align__(16) f16 kt[2][4096];   // 2 x 8 KB fragment-order tiles
    __shared__ u16 gcl[GPB * 32];
    __shared__ int meta[GPB];

    const int tid  = threadIdx.x;
    const int w    = tid >> 6;
    const int lane = tid & 63;
    const int l31  = lane & 31;
    const int lhi  = lane >> 5;

    // XCD co-location: all 4 qb-siblings of a kc share wg%8 (same XCD under
    // round-robin dispatch) -> key chunk fetched into one L2 once. Perf-only.
    const int wg   = blockIdx.x;
    const int xcd  = wg & 7;
    const int slot = wg >> 3;            // 0..159
    const int qb   = slot & 3;
    const int kc   = xcd * (KC / 8) + (slot >> 2);   // 0..319
    const int g0   = kc * GPB;

    // chunk's class labels -> LDS
    for (int i = tid; i < GPB * 32; i += 256) gcl[i] = kcls[g0 * 32 + i];

    // A fragments: wave w owns queries qb*256 + w*64 + {0..63}
    f16x8 A0[8], A1[8];
    {
        const f16* qa = qf2 + (size_t)(qb * 8 + w * 2) * 4096 + lane * 8;
        #pragma unroll
        for (int kk = 0; kk < 8; ++kk) {
            A0[kk] = *(const f16x8*)(qa + kk * 512);
            A1[kk] = *(const f16x8*)(qa + 4096 + kk * 512);
        }
    }
    const int q00 = qb * 256 + w * 64;
    const int q01 = q00 + 32;

    __syncthreads();                       // gcl ready
    if (tid < GPB) {                       // per-group (ca, cb, split), <=2 runs
        const int base = tid * 32;
        int ca = gcl[base], split = 32, cb = ca;
        for (int j = 1; j < 32; ++j) {
            const int c2 = gcl[base + j];
            if (c2 != ca) { split = j; cb = c2; break; }
        }
        meta[tid] = ca | (cb << 11) | (split << 22);
    }

    // prologue: stage tile 0, prefetch tile 1 into regs
    {
        const f16* src = kf2 + (size_t)g0 * 4096 + tid * 8;
        *(f16x8*)(&kt[0][tid * 8])        = *(const f16x8*)(src);
        *(f16x8*)(&kt[0][2048 + tid * 8]) = *(const f16x8*)(src + 2048);
    }
    f16x8 s0 = {}, s1 = {};
    if (GPB > 1) {
        const f16* src = kf2 + (size_t)(g0 + 1) * 4096 + tid * 8;
        s0 = *(const f16x8*)(src);
        s1 = *(const f16x8*)(src + 2048);
    }

    float sums0[16], sums1[16];
    ZEROSUMS;
    int cur = -1;

    for (int i = 0; i < GPB; ++i) {
        __syncthreads();                   // kt[i&1] + meta ready; old reads done
        const int m     = meta[i];         // wave-uniform LDS read
        const int ca    = m & 0x7FF;
        const int cb    = (m >> 11) & 0x7FF;
        const int split = m >> 22;

        if (i + 1 < GPB) {                 // write landed tile, issue i+2
            *(f16x8*)(&kt[(i + 1) & 1][tid * 8])        = s0;
            *(f16x8*)(&kt[(i + 1) & 1][2048 + tid * 8]) = s1;
            if (i + 2 < GPB) {
                const f16* src = kf2 + (size_t)(g0 + i + 2) * 4096 + tid * 8;
                s0 = *(const f16x8*)(src);
                s1 = *(const f16x8*)(src + 2048);
            }
        }

        f32x16 c0 = {}, c1 = {};
        const f16* kb = kt[i & 1];
        __builtin_amdgcn_s_setprio(1);
        #pragma unroll
        for (int kk = 0; kk < 8; ++kk) {
            const f16x8 Bf = *(const f16x8*)(kb + kk * 512 + lane * 8);
            c0 = __builtin_amdgcn_mfma_f32_32x32x16_f16(A0[kk], Bf, c0, 0, 0, 0);
            c1 = __builtin_amdgcn_mfma_f32_32x32x16_f16(A1[kk], Bf, c1, 0, 0, 0);
        }
        __builtin_amdgcn_s_setprio(0);

        if (ca != cur) {                   // wave-uniform
            if (cur >= 0) FLUSH(cur);
            ZEROSUMS;
            cur = ca;
        }
        if (split == 32) {
            #pragma unroll
            for (int r = 0; r < 16; ++r) {
                sums0[r] += __builtin_amdgcn_exp2f(c0[r]);
                sums1[r] += __builtin_amdgcn_exp2f(c1[r]);
            }
        } else {                           // boundary group: 2 runs
            const bool lo = l31 < split;
            #pragma unroll
            for (int r = 0; r < 16; ++r) {
                sums0[r] += lo ? __builtin_amdgcn_exp2f(c0[r]) : 0.0f;
                sums1[r] += lo ? __builtin_amdgcn_exp2f(c1[r]) : 0.0f;
            }
            FLUSH(cur);
            ZEROSUMS;
            cur = cb;
            #pragma unroll
            for (int r = 0; r < 16; ++r) {
                sums0[r] += lo ? 0.0f : __builtin_amdgcn_exp2f(c0[r]);
                sums1[r] += lo ? 0.0f : __builtin_amdgcn_exp2f(c1[r]);
            }
        }
    }
    if (cur >= 0) FLUSH(cur);
}

// ---- epilogue 1: partial class-sums per query (100 blocks x 1024 thr) ----
__global__ __launch_bounds__(1024)
void k_qsum(const float* __restrict__ out_t, float* __restrict__ partial) {
    const int cb = blockIdx.x;
    const int q  = threadIdx.x;
    const float* p = out_t + (size_t)cb * CSUM * B_Q + q;
    float s = 0.0f;
    #pragma unroll
    for (int i = 0; i < CSUM; ++i) s += p[(size_t)i * B_Q];
    partial[cb * B_Q + q] = s;
}

// ---- epilogue 2: 64x64 scaled transpose tiles ----
__global__ __launch_bounds__(256)
void k_norm_t(const float* __restrict__ out_t, const float* __restrict__ partial,
              float* __restrict__ out) {
    __shared__ float tile[64 * 65];
    __shared__ float invq[64];
    const int tid  = threadIdx.x;
    const int w    = tid >> 6;
    const int lane = tid & 63;
    const int q0   = blockIdx.x * 64;
    const int c0   = blockIdx.y * 64;

    if (tid < 64) {
        float s = 0.0f;
        for (int cb = 0; cb < NCB; ++cb) s += partial[cb * B_Q + q0 + tid];
        invq[tid] = 1.0f / s;
    }
    #pragma unroll
    for (int i = 0; i < 16; ++i) {
        const int cidx = c0 + w * 16 + i;
        const float v = (cidx < N_CLS) ? out_t[(size_t)cidx * B_Q + q0 + lane] : 0.0f;
        tile[lane * 65 + w * 16 + i] = v;
    }
    __syncthreads();
    #pragma unroll
    for (int j = 0; j < 16; ++j) {
        const int r    = w * 16 + j;
        const int cidx = c0 + lane;
        if (cidx < N_CLS)
            out[(size_t)(q0 + r) * N_CLS + cidx] = tile[r * 65 + lane] * invq[r];
    }
}

extern "C" void kernel_launch(void* const* d_in, const int* in_sizes, int n_in,
                              void* d_out, int out_size, void* d_ws, size_t ws_size,
                              hipStream_t stream) {
    const float* qm     = (const float*)d_in[0];
    const float* km     = (const float*)d_in[1];
    const int*   labels = (const int*)d_in[2];
    float* out = (float*)d_out;

    char* p = (char*)d_ws;
    f16*   kf2     = (f16*)p;   p += (size_t)NPAD * DIM * 2;        // 26.2 MB
    f16*   qf2     = (f16*)p;   p += (size_t)B_Q * DIM * 2;         // 256 KB
    float* out_t   = (float*)p; p += (size_t)N_CLS * B_Q * 4;       // 4.1 MB
    // NOTE: class-1000 (dummy) bucket row == out_t + 1000*B_Q == partial base.
    // class_gemm4's dummy atomics land here; k_qsum overwrites it afterwards.
    float* partial = (float*)p; p += (size_t)NCB * B_Q * 4;         // 400 KB
    uint*  ghist   = (uint*)p;  p += N_CLS * 4;
    uint*  cursor  = (uint*)p;  p += N_CLS * 4;
    u16*   kcls    = (u16*)p;   p += (size_t)NPAD * 2;              // 205 KB

    hipMemsetAsync(ghist, 0, N_CLS * sizeof(uint), stream);
    hipMemsetAsync(out_t, 0, (size_t)N_CLS * B_Q * sizeof(float), stream);

    hipLaunchKernelGGL(k_hist, dim3(128), dim3(256), 0, stream, labels, ghist);
    hipLaunchKernelGGL(k_scan, dim3(1), dim3(1024), 0, stream, ghist, cursor);

    const int prows = NPAD + B_Q;                  // keys + dummies + queries
    hipLaunchKernelGGL(k_prep, dim3((prows * 64 + 255) / 256), dim3(256), 0, stream,
                       qm, km, labels, cursor, kf2, qf2, kcls);

    hipLaunchKernelGGL(class_gemm4, dim3(4 * KC), dim3(256), 0, stream,
                       kf2, qf2, kcls, out_t);

    hipLaunchKernelGGL(k_qsum, dim3(NCB), dim3(1024), 0, stream, out_t, partial);
    hipLaunchKernelGGL(k_norm_t, dim3(B_Q / 64, (N_CLS + 63) / 64), dim3(256), 0, stream,
                       out_t, partial, out);
}

// Round 8
// 156.504 us; speedup vs baseline: 1.8024x; 1.8024x over previous
//
#include <hip/hip_runtime.h>
#include <math.h>

typedef _Float16 f16;
typedef _Float16 f16x8 __attribute__((ext_vector_type(8)));
typedef float    f32x16 __attribute__((ext_vector_type(16)));
typedef unsigned int uint;
typedef unsigned short u16;

#define B_Q     1024
#define DIM     128
#define N_KEYS  100000
#define NPAD    102400          /* padded to 3200 groups of 32 */
#define NGP     (NPAD / 32)     /* 3200 */
#define KC      320             /* key chunks */
#define GPB     (NGP / KC)      /* 10 groups per block */
#define N_CLS   1000
#define QSCALE  11.541560327111707f /* 8/ln2: fold beta*log2(e) into queries */
#define CSUM    10
#define NCB     (N_CLS / CSUM)  /* 100 */

// ---- label histogram ----
__global__ void k_hist(const int* __restrict__ labels, uint* __restrict__ ghist) {
    __shared__ uint lh[N_CLS];
    for (int i = threadIdx.x; i < N_CLS; i += blockDim.x) lh[i] = 0;
    __syncthreads();
    const int stride = gridDim.x * blockDim.x;
    for (int i = blockIdx.x * blockDim.x + threadIdx.x; i < N_KEYS; i += stride)
        atomicAdd(&lh[labels[i]], 1u);
    __syncthreads();
    for (int i = threadIdx.x; i < N_CLS; i += blockDim.x)
        if (lh[i]) atomicAdd(&ghist[i], lh[i]);
}

// ---- exclusive scan -> cursor ----
__global__ void k_scan(const uint* __restrict__ ghist, uint* __restrict__ cursor) {
    __shared__ uint s[1024];
    const int t = threadIdx.x;
    const uint v = (t < N_CLS) ? ghist[t] : 0u;
    s[t] = v; __syncthreads();
    for (int o = 1; o < 1024; o <<= 1) {
        const uint x = (t >= o) ? s[t - o] : 0u;
        __syncthreads();
        s[t] += x;
        __syncthreads();
    }
    if (t < N_CLS) cursor[t] = s[t] - v;
}

// ---- fused prep: normalize, f16, scatter into MFMA-fragment order; dummies ----
// layout per 32-row group: [kk(8)][lane(64)][j(8)] f16; (kk,lane,j) =
// row (lane&31), dim kk*16 + (lane>>5)*8 + j.
__global__ void k_prep(const float* __restrict__ qm, const float* __restrict__ km,
                       const int* __restrict__ labels, uint* __restrict__ cursor,
                       f16* __restrict__ kf2, f16* __restrict__ qf2,
                       u16* __restrict__ kcls) {
    const int gid  = blockIdx.x * blockDim.x + threadIdx.x;
    const int n    = gid >> 6;
    const int lane = threadIdx.x & 63;
    if (n >= NPAD + B_Q) return;
    const bool isq   = n >= NPAD;
    const bool dummy = !isq && n >= N_KEYS;

    float a = 0.0f, b = 0.0f;
    if (!dummy) {
        const float* row = isq ? qm + (size_t)(n - NPAD) * DIM
                               : km + (size_t)n * DIM;
        a = row[lane]; b = row[lane + 64];
    }
    float ss = a * a + b * b;
    #pragma unroll
    for (int o = 32; o >= 1; o >>= 1) ss += __shfl_xor(ss, o);
    const float rn = (isq ? QSCALE : 1.0f) / fmaxf(sqrtf(ss), 1e-12f);

    int pos;
    if (isq)        pos = n - NPAD;
    else if (dummy) { pos = n; if (lane == 0) kcls[pos] = (u16)N_CLS; }
    else {
        const int lab = labels[n];
        if (lane == 0) pos = (int)atomicAdd(&cursor[lab], 1u);
        pos = __shfl(pos, 0);
        if (lane == 0) kcls[pos] = (u16)lab;
    }

    const float va = a * rn, vb = b * rn;   // dummy rows stay exactly 0
    f16x8 hv;
    #pragma unroll
    for (int j = 0; j < 8; ++j) {
        const int src = (lane & 15) * 8 + j;        // 0..127
        const float xa = __shfl(va, src & 63);
        const float xb = __shfl(vb, src & 63);
        hv[j] = (f16)((src < 64) ? xa : xb);
    }
    if (lane < 16) {
        f16* dst = isq ? qf2 : kf2;
        const int kk  = lane >> 1;
        const int lhi = lane & 1;
        *(f16x8*)(dst + (size_t)(pos >> 5) * 4096 + kk * 512 +
                  ((lhi << 5) + (pos & 31)) * 8) = hv;
    }
}

// ---- main: 1280 blocks (XCD co-located), 4 waves, 2 q-subtiles/wave,
// LDS-precomputed class metadata, double-buffered fragment-order tiles.
#define FLUSH(C) {                                                            \
    _Pragma("unroll")                                                         \
    for (int r = 0; r < 16; ++r) {                                            \
        float t0 = sums0[r], t1 = sums1[r];                                   \
        t0 += __shfl_xor(t0,1); t0 += __shfl_xor(t0,2); t0 += __shfl_xor(t0,4);\
        t0 += __shfl_xor(t0,8); t0 += __shfl_xor(t0,16);                      \
        t1 += __shfl_xor(t1,1); t1 += __shfl_xor(t1,2); t1 += __shfl_xor(t1,4);\
        t1 += __shfl_xor(t1,8); t1 += __shfl_xor(t1,16);                      \
        const int row = (r & 3) + 8 * (r >> 2) + 4 * lhi;                     \
        if (l31 == row) {                                                     \
            atomicAdd(&out_t[(size_t)(C) * B_Q + q00 + row], t0);             \
            atomicAdd(&out_t[(size_t)(C) * B_Q + q01 + row], t1);             \
        }                                                                     \
    } }
#define ZEROSUMS { _Pragma("unroll") for (int r=0;r<16;++r){sums0[r]=0.f;sums1[r]=0.f;} }

__global__ __launch_bounds__(256, 2)   // round-6-proven: 116 VGPR, zero spill
void class_gemm4(const f16* __restrict__ kf2, const f16* __restrict__ qf2,
                 const u16* __restrict__ kcls, float* __restrict__ out_t) {
    __shared__ __align__(16) f16 kt[2][4096];   // 2 x 8 KB fragment-order tiles
    __shared__ u16 gcl[GPB * 32];
    __shared__ int meta[GPB];

    const int tid  = threadIdx.x;
    const int w    = tid >> 6;
    const int lane = tid & 63;
    const int l31  = lane & 31;
    const int lhi  = lane >> 5;

    // XCD co-location: all 4 qb-siblings of a kc share wg%8 (same XCD under
    // round-robin dispatch) -> key chunk fetched into one L2 once. Perf-only.
    const int wg   = blockIdx.x;
    const int xcd  = wg & 7;
    const int slot = wg >> 3;            // 0..159
    const int qb   = slot & 3;
    const int kc   = xcd * (KC / 8) + (slot >> 2);   // 0..319
    const int g0   = kc * GPB;

    // chunk's class labels -> LDS
    for (int i = tid; i < GPB * 32; i += 256) gcl[i] = kcls[g0 * 32 + i];

    // A fragments: wave w owns queries qb*256 + w*64 + {0..63}
    f16x8 A0[8], A1[8];
    {
        const f16* qa = qf2 + (size_t)(qb * 8 + w * 2) * 4096 + lane * 8;
        #pragma unroll
        for (int kk = 0; kk < 8; ++kk) {
            A0[kk] = *(const f16x8*)(qa + kk * 512);
            A1[kk] = *(const f16x8*)(qa + 4096 + kk * 512);
        }
    }
    const int q00 = qb * 256 + w * 64;
    const int q01 = q00 + 32;

    __syncthreads();                       // gcl ready
    if (tid < GPB) {                       // per-group (ca, cb, split), <=2 runs
        const int base = tid * 32;
        int ca = gcl[base], split = 32, cb = ca;
        for (int j = 1; j < 32; ++j) {
            const int c2 = gcl[base + j];
            if (c2 != ca) { split = j; cb = c2; break; }
        }
        meta[tid] = ca | (cb << 11) | (split << 22);
    }

    // prologue: stage tile 0, prefetch tile 1 into regs
    {
        const f16* src = kf2 + (size_t)g0 * 4096 + tid * 8;
        *(f16x8*)(&kt[0][tid * 8])        = *(const f16x8*)(src);
        *(f16x8*)(&kt[0][2048 + tid * 8]) = *(const f16x8*)(src + 2048);
    }
    f16x8 s0 = {}, s1 = {};
    if (GPB > 1) {
        const f16* src = kf2 + (size_t)(g0 + 1) * 4096 + tid * 8;
        s0 = *(const f16x8*)(src);
        s1 = *(const f16x8*)(src + 2048);
    }

    float sums0[16], sums1[16];
    ZEROSUMS;
    int cur = -1;

    for (int i = 0; i < GPB; ++i) {
        __syncthreads();                   // kt[i&1] + meta ready; old reads done
        const int m     = meta[i];         // wave-uniform LDS read
        const int ca    = m & 0x7FF;
        const int cb    = (m >> 11) & 0x7FF;
        const int split = m >> 22;

        if (i + 1 < GPB) {                 // write landed tile, issue i+2
            *(f16x8*)(&kt[(i + 1) & 1][tid * 8])        = s0;
            *(f16x8*)(&kt[(i + 1) & 1][2048 + tid * 8]) = s1;
            if (i + 2 < GPB) {
                const f16* src = kf2 + (size_t)(g0 + i + 2) * 4096 + tid * 8;
                s0 = *(const f16x8*)(src);
                s1 = *(const f16x8*)(src + 2048);
            }
        }

        f32x16 c0 = {}, c1 = {};
        const f16* kb = kt[i & 1];
        __builtin_amdgcn_s_setprio(1);
        #pragma unroll
        for (int kk = 0; kk < 8; ++kk) {
            const f16x8 Bf = *(const f16x8*)(kb + kk * 512 + lane * 8);
            c0 = __builtin_amdgcn_mfma_f32_32x32x16_f16(A0[kk], Bf, c0, 0, 0, 0);
            c1 = __builtin_amdgcn_mfma_f32_32x32x16_f16(A1[kk], Bf, c1, 0, 0, 0);
        }
        __builtin_amdgcn_s_setprio(0);

        if (ca != cur) {                   // wave-uniform
            if (cur >= 0) FLUSH(cur);
            ZEROSUMS;
            cur = ca;
        }
        if (split == 32) {
            #pragma unroll
            for (int r = 0; r < 16; ++r) {
                sums0[r] += __builtin_amdgcn_exp2f(c0[r]);
                sums1[r] += __builtin_amdgcn_exp2f(c1[r]);
            }
        } else {                           // boundary group: 2 runs
            const bool lo = l31 < split;
            #pragma unroll
            for (int r = 0; r < 16; ++r) {
                sums0[r] += lo ? __builtin_amdgcn_exp2f(c0[r]) : 0.0f;
                sums1[r] += lo ? __builtin_amdgcn_exp2f(c1[r]) : 0.0f;
            }
            FLUSH(cur);
            ZEROSUMS;
            cur = cb;
            #pragma unroll
            for (int r = 0; r < 16; ++r) {
                sums0[r] += lo ? 0.0f : __builtin_amdgcn_exp2f(c0[r]);
                sums1[r] += lo ? 0.0f : __builtin_amdgcn_exp2f(c1[r]);
            }
        }
    }
    if (cur >= 0) FLUSH(cur);
}

// ---- epilogue 1: partial class-sums per query (100 blocks x 1024 thr) ----
__global__ __launch_bounds__(1024)
void k_qsum(const float* __restrict__ out_t, float* __restrict__ partial) {
    const int cb = blockIdx.x;
    const int q  = threadIdx.x;
    const float* p = out_t + (size_t)cb * CSUM * B_Q + q;
    float s = 0.0f;
    #pragma unroll
    for (int i = 0; i < CSUM; ++i) s += p[(size_t)i * B_Q];
    partial[cb * B_Q + q] = s;
}

// ---- epilogue 2: 64x64 scaled transpose tiles ----
__global__ __launch_bounds__(256)
void k_norm_t(const float* __restrict__ out_t, const float* __restrict__ partial,
              float* __restrict__ out) {
    __shared__ float tile[64 * 65];
    __shared__ float invq[64];
    const int tid  = threadIdx.x;
    const int w    = tid >> 6;
    const int lane = tid & 63;
    const int q0   = blockIdx.x * 64;
    const int c0   = blockIdx.y * 64;

    if (tid < 64) {
        float s = 0.0f;
        for (int cb = 0; cb < NCB; ++cb) s += partial[cb * B_Q + q0 + tid];
        invq[tid] = 1.0f / s;
    }
    #pragma unroll
    for (int i = 0; i < 16; ++i) {
        const int cidx = c0 + w * 16 + i;
        const float v = (cidx < N_CLS) ? out_t[(size_t)cidx * B_Q + q0 + lane] : 0.0f;
        tile[lane * 65 + w * 16 + i] = v;
    }
    __syncthreads();
    #pragma unroll
    for (int j = 0; j < 16; ++j) {
        const int r    = w * 16 + j;
        const int cidx = c0 + lane;
        if (cidx < N_CLS)
            out[(size_t)(q0 + r) * N_CLS + cidx] = tile[r * 65 + lane] * invq[r];
    }
}

extern "C" void kernel_launch(void* const* d_in, const int* in_sizes, int n_in,
                              void* d_out, int out_size, void* d_ws, size_t ws_size,
                              hipStream_t stream) {
    const float* qm     = (const float*)d_in[0];
    const float* km     = (const float*)d_in[1];
    const int*   labels = (const int*)d_in[2];
    float* out = (float*)d_out;

    char* p = (char*)d_ws;
    f16*   kf2     = (f16*)p;   p += (size_t)NPAD * DIM * 2;        // 26.2 MB
    f16*   qf2     = (f16*)p;   p += (size_t)B_Q * DIM * 2;         // 256 KB
    float* out_t   = (float*)p; p += (size_t)N_CLS * B_Q * 4;       // 4.1 MB
    // NOTE: class-1000 (dummy) bucket row == out_t + 1000*B_Q == partial base.
    // class_gemm4's dummy atomics land here; k_qsum overwrites it afterwards.
    float* partial = (float*)p; p += (size_t)NCB * B_Q * 4;         // 400 KB
    uint*  ghist   = (uint*)p;  p += N_CLS * 4;
    uint*  cursor  = (uint*)p;  p += N_CLS * 4;
    u16*   kcls    = (u16*)p;   p += (size_t)NPAD * 2;              // 205 KB

    hipMemsetAsync(ghist, 0, N_CLS * sizeof(uint), stream);
    hipMemsetAsync(out_t, 0, (size_t)N_CLS * B_Q * sizeof(float), stream);

    hipLaunchKernelGGL(k_hist, dim3(128), dim3(256), 0, stream, labels, ghist);
    hipLaunchKernelGGL(k_scan, dim3(1), dim3(1024), 0, stream, ghist, cursor);

    const int prows = NPAD + B_Q;                  // keys + dummies + queries
    hipLaunchKernelGGL(k_prep, dim3((prows * 64 + 255) / 256), dim3(256), 0, stream,
                       qm, km, labels, cursor, kf2, qf2, kcls);

    hipLaunchKernelGGL(class_gemm4, dim3(4 * KC), dim3(256), 0, stream,
                       kf2, qf2, kcls, out_t);

    hipLaunchKernelGGL(k_qsum, dim3(NCB), dim3(1024), 0, stream, out_t, partial);
    hipLaunchKernelGGL(k_norm_t, dim3(B_Q / 64, (N_CLS + 63) / 64), dim3(256), 0, stream,
                       out_t, partial, out);
}